// Round 9
// baseline (472.498 us; speedup 1.0000x reference)
//
#include <hip/hip_runtime.h>
#include <hip/hip_bf16.h>
#include <cstdint>

#define SEQ 4096
#define NB 4
#define DIM 1024
#define MTOT (NB * SEQ)   // 16384
constexpr size_t EL = (size_t)MTOT * DIM;

using u16x8  = __attribute__((ext_vector_type(8))) unsigned short;
using bf16x8 = __attribute__((ext_vector_type(8))) __bf16;
using f32x4  = __attribute__((ext_vector_type(4))) float;

__device__ __forceinline__ unsigned short f2bf(float f) {
  return __builtin_bit_cast(unsigned short, __float2bfloat16(f));  // native RNE cvt
}

__device__ __forceinline__ void gload16(const unsigned short* g, unsigned short* l) {
  __builtin_amdgcn_global_load_lds(
      (const __attribute__((address_space(1))) unsigned int*)g,
      (__attribute__((address_space(3))) unsigned int*)l, 16, 0, 0);
}
__device__ __forceinline__ void stage_half(const unsigned short* gsrc, size_t ld,
                                           unsigned short* ldst) {
  gload16(gsrc, ldst);
  gload16(gsrc + 64 * ld, ldst + 64 * 64);
}

#define BAR()   __builtin_amdgcn_s_barrier()
#define FENCE() asm volatile("" ::: "memory")

// ------- prep_all: x cvt + lsum zero + bias concat + 3x W transpose -------
__global__ __launch_bounds__(256) void prep_all(
    const float* __restrict__ x, unsigned short* __restrict__ xb,
    const float* __restrict__ Wq, const float* __restrict__ Wk,
    const float* __restrict__ Wv, unsigned short* __restrict__ WT,
    const float* __restrict__ bq, const float* __restrict__ bk,
    const float* __restrict__ bv, float* __restrict__ bc,
    float* __restrict__ l) {
  __shared__ float tile[32][33];
  const int bid = (int)blockIdx.x;
  const int t = threadIdx.x;
  if (bid < (int)(EL / 1024)) {
    const size_t gid = (size_t)bid * 256 + t;
    const size_t i = gid * 4;
    float4 v = *(const float4*)(x + i);
    ushort4 o;
    o.x = f2bf(v.x); o.y = f2bf(v.y); o.z = f2bf(v.z); o.w = f2bf(v.w);
    *(ushort4*)(xb + i) = o;
    if (gid < MTOT) l[gid] = 0.f;
    if (gid < 3 * DIM)
      bc[gid] = gid < DIM ? bq[gid] : gid < 2 * DIM ? bk[gid - DIM] : bv[gid - 2 * DIM];
  } else {
    const int wb = bid - (int)(EL / 1024);      // 0..3071
    const int z = wb >> 10;                      // 0..2
    const float* W = z == 0 ? Wq : z == 1 ? Wk : Wv;
    unsigned short* O = WT + (size_t)z * DIM * DIM;
    const int rem = wb & 1023;
    const int e0 = (rem & 31) * 32, d0 = (rem >> 5) * 32;
    const int tx = t & 31, ty = t >> 5;          // 32 x 8
#pragma unroll
    for (int j = 0; j < 32; j += 8)
      tile[ty + j][tx] = W[(size_t)(d0 + ty + j) * DIM + e0 + tx];
    __syncthreads();
#pragma unroll
    for (int j = 0; j < 32; j += 8)
      O[(size_t)(e0 + ty + j) * DIM + d0 + tx] = f2bf(tile[tx][ty + j]);
  }
}

// ============ 256x256 8-phase BT-GEMM body: C[M,N] = A[M,K] * B^T ============
// 512 thr = 8 waves (2M x 4N); wave tile 128x64; BK=64; LDS 128KiB (2 K-tile bufs).
// Race-free R6/R8 schedule. Body is re-entrant: __syncthreads() at entry fences
// the previous call's epilogue LDS reads against this call's staging.
enum { EPI_QKV = 0, EPI_EXP = 1, EPI_PV = 2 };

template <int EPI>
__device__ __forceinline__ void gemm_body(
    const unsigned short* __restrict__ A, const unsigned short* __restrict__ B,
    void* __restrict__ C, const float* __restrict__ bias, float* __restrict__ lsum,
    int K, int lda, int ldb, int ldc, float scale,
    int row0, int col0, int bz, long sA, long sB, long sC) {
  __shared__ unsigned short sm[2][2][256 * 64];   // 128 KiB (shared across calls)
  const int t    = threadIdx.x;
  const int lane = t & 63;
  const int wave = t >> 6;
  const int wm   = wave >> 2;          // 0..1  (M half)
  const int wn   = wave & 3;           // 0..3  (N quarter)
  const int fr   = lane & 15;
  const int g    = lane >> 4;          // k-group
  const int xr   = (fr & 7) << 4;      // read-side XOR

  __syncthreads();   // re-entry fence (prev epilogue readers vs new staging)

  const unsigned short* Ab = A + (size_t)bz * (size_t)sA;
  const unsigned short* Bb = B + (size_t)bz * (size_t)sB;

  const int srow = t >> 3;
  const int scol = ((((t & 7) << 4) ^ ((srow & 7) << 4)) >> 1);
  const unsigned short* gA = Ab + (size_t)(row0 + srow) * (size_t)lda + scol;
  const unsigned short* gB = Bb + (size_t)(col0 + srow) * (size_t)ldb + scol;

  const int arow = wm * 128 + fr;
  const int brow = wn * 64 + fr;
  const int c0 = (((g << 4)) ^ xr) >> 1;
  const int c1 = ((64 | (g << 4)) ^ xr) >> 1;

  f32x4 acc[8][4];
  const f32x4 z4 = {0.f, 0.f, 0.f, 0.f};
#pragma unroll
  for (int i = 0; i < 8; ++i)
#pragma unroll
    for (int j = 0; j < 4; ++j) acc[i][j] = z4;

  const int nt = K >> 6;

  stage_half(gA, lda, &sm[0][0][wave * 512]);
  stage_half(gA + 128 * (size_t)lda, lda, &sm[0][0][8192 + wave * 512]);
  stage_half(gB, ldb, &sm[0][1][wave * 512]);
  stage_half(gB + 128 * (size_t)ldb, ldb, &sm[0][1][8192 + wave * 512]);
  if (nt > 1) {
    stage_half(gB + 64, ldb, &sm[1][1][wave * 512]);
    stage_half(gB + 128 * (size_t)ldb + 64, ldb, &sm[1][1][8192 + wave * 512]);
    stage_half(gA + 64, lda, &sm[1][0][wave * 512]);
    asm volatile("s_waitcnt vmcnt(6)" ::: "memory");
  } else {
    asm volatile("s_waitcnt vmcnt(0)" ::: "memory");
  }
  BAR(); FENCE();

  bf16x8 a0[4][2], a1[4][2], b0[2][2], b1[2][2];

  for (int kt = 0; kt < nt; ++kt) {
    const int p = kt & 1;
    const unsigned short* As  = sm[p][0];
    const unsigned short* Bs2 = sm[p][1];

    // P1: read A0-3 + B0-1 (12), stage T(kt+1).A-hi
#pragma unroll
    for (int mi = 0; mi < 4; ++mi) {
      a0[mi][0] = *(const bf16x8*)(As + (arow + mi * 16) * 64 + c0);
      a0[mi][1] = *(const bf16x8*)(As + (arow + mi * 16) * 64 + c1);
    }
#pragma unroll
    for (int ni = 0; ni < 2; ++ni) {
      b0[ni][0] = *(const bf16x8*)(Bs2 + (brow + ni * 16) * 64 + c0);
      b0[ni][1] = *(const bf16x8*)(Bs2 + (brow + ni * 16) * 64 + c1);
    }
    if (kt + 1 < nt)
      stage_half(gA + 128 * (size_t)lda + (size_t)(kt + 1) * 64, lda,
                 &sm[p ^ 1][0][8192 + wave * 512]);
    FENCE(); BAR(); FENCE();
    __builtin_amdgcn_s_setprio(1);
#pragma unroll
    for (int mi = 0; mi < 4; ++mi)
#pragma unroll
      for (int ni = 0; ni < 2; ++ni) {
        acc[mi][ni] = __builtin_amdgcn_mfma_f32_16x16x32_bf16(a0[mi][0], b0[ni][0], acc[mi][ni], 0, 0, 0);
        acc[mi][ni] = __builtin_amdgcn_mfma_f32_16x16x32_bf16(a0[mi][1], b0[ni][1], acc[mi][ni], 0, 0, 0);
      }
    __builtin_amdgcn_s_setprio(0);
    FENCE(); BAR(); FENCE();

    // P2: read B2-3 (4)
#pragma unroll
    for (int ni = 0; ni < 2; ++ni) {
      b1[ni][0] = *(const bf16x8*)(Bs2 + (brow + (ni + 2) * 16) * 64 + c0);
      b1[ni][1] = *(const bf16x8*)(Bs2 + (brow + (ni + 2) * 16) * 64 + c1);
    }
    FENCE(); BAR(); FENCE();
    __builtin_amdgcn_s_setprio(1);
#pragma unroll
    for (int mi = 0; mi < 4; ++mi)
#pragma unroll
      for (int ni = 0; ni < 2; ++ni) {
        acc[mi][ni + 2] = __builtin_amdgcn_mfma_f32_16x16x32_bf16(a0[mi][0], b1[ni][0], acc[mi][ni + 2], 0, 0, 0);
        acc[mi][ni + 2] = __builtin_amdgcn_mfma_f32_16x16x32_bf16(a0[mi][1], b1[ni][1], acc[mi][ni + 2], 0, 0, 0);
      }
    __builtin_amdgcn_s_setprio(0);
    FENCE(); BAR(); FENCE();

    // P3: read A4-7 (8), stage T(kt+2).B-lo
#pragma unroll
    for (int mi = 0; mi < 4; ++mi) {
      a1[mi][0] = *(const bf16x8*)(As + (arow + (mi + 4) * 16) * 64 + c0);
      a1[mi][1] = *(const bf16x8*)(As + (arow + (mi + 4) * 16) * 64 + c1);
    }
    if (kt + 2 < nt)
      stage_half(gB + (size_t)(kt + 2) * 64, ldb, &sm[p][1][wave * 512]);
    FENCE(); BAR(); FENCE();
    __builtin_amdgcn_s_setprio(1);
#pragma unroll
    for (int mi = 0; mi < 4; ++mi)
#pragma unroll
      for (int ni = 0; ni < 2; ++ni) {
        acc[mi + 4][ni] = __builtin_amdgcn_mfma_f32_16x16x32_bf16(a1[mi][0], b0[ni][0], acc[mi + 4][ni], 0, 0, 0);
        acc[mi + 4][ni] = __builtin_amdgcn_mfma_f32_16x16x32_bf16(a1[mi][1], b0[ni][1], acc[mi + 4][ni], 0, 0, 0);
      }
    __builtin_amdgcn_s_setprio(0);
    FENCE(); BAR(); FENCE();

    // P4: stage T(kt+2).{B-hi,A-lo}; counted vmcnt; MFMA q4
    if (kt + 2 < nt) {
      stage_half(gB + 128 * (size_t)ldb + (size_t)(kt + 2) * 64, ldb,
                 &sm[p][1][8192 + wave * 512]);
      stage_half(gA + (size_t)(kt + 2) * 64, lda, &sm[p][0][wave * 512]);
      asm volatile("s_waitcnt vmcnt(6)" ::: "memory");
    } else {
      asm volatile("s_waitcnt vmcnt(0)" ::: "memory");
    }
    FENCE(); BAR(); FENCE();
    __builtin_amdgcn_s_setprio(1);
#pragma unroll
    for (int mi = 0; mi < 4; ++mi)
#pragma unroll
      for (int ni = 0; ni < 2; ++ni) {
        acc[mi + 4][ni + 2] = __builtin_amdgcn_mfma_f32_16x16x32_bf16(a1[mi][0], b1[ni][0], acc[mi + 4][ni + 2], 0, 0, 0);
        acc[mi + 4][ni + 2] = __builtin_amdgcn_mfma_f32_16x16x32_bf16(a1[mi][1], b1[ni][1], acc[mi + 4][ni + 2], 0, 0, 0);
      }
    __builtin_amdgcn_s_setprio(0);
    FENCE(); BAR(); FENCE();
  }

  // ===================== LDS-staged coalesced epilogues =====================
  char* Lb = (char*)&sm[0][0][0];
  const int rb = (lane >> 4) * 4;

  if constexpr (EPI == EPI_QKV) {
    const int which = col0 >> 10;            // 0=Q 1=K 2=V
    const int lc0   = col0 & 1023;
    unsigned short* Co = (unsigned short*)C + (size_t)which * EL;
    if (which < 2) {
      float bb[4];
#pragma unroll
      for (int ni = 0; ni < 4; ++ni) bb[ni] = bias[col0 + wn * 64 + ni * 16 + fr];
#pragma unroll
      for (int mi = 0; mi < 8; ++mi) {
        const int r0 = wm * 128 + mi * 16 + rb;
#pragma unroll
        for (int ni = 0; ni < 4; ++ni) {
          const int c = wn * 64 + ni * 16 + fr;
#pragma unroll
          for (int j = 0; j < 4; ++j) {
            const int r = r0 + j;
            *(unsigned short*)(Lb + r * 512 + ((c * 2) ^ ((r & 7) << 4))) =
                f2bf(acc[mi][ni][j] + bb[ni]);
          }
        }
      }
      __syncthreads();
#pragma unroll 4
      for (int i = 0; i < 16; ++i) {
        const int G = i * 512 + t;
        const int r = G >> 5, c16 = G & 31;
        u16x8 v = *(const u16x8*)(Lb + r * 512 + ((c16 * 16) ^ ((r & 7) << 4)));
        *(u16x8*)(Co + (size_t)(row0 + r) * DIM + lc0 + c16 * 8) = v;
      }
    } else {
      // V: store transposed through col-major LDS tile
#pragma unroll
      for (int ni = 0; ni < 4; ++ni) {
        const int c = wn * 64 + ni * 16 + fr;
        const float bb = bias[col0 + c];
#pragma unroll
        for (int mi = 0; mi < 8; ++mi) {
          const int r0 = wm * 128 + mi * 16 + rb;
          ushort4 pk;
          pk.x = f2bf(acc[mi][ni][0] + bb);
          pk.y = f2bf(acc[mi][ni][1] + bb);
          pk.z = f2bf(acc[mi][ni][2] + bb);
          pk.w = f2bf(acc[mi][ni][3] + bb);
          *(ushort4*)(Lb + c * 512 + ((r0 * 2) ^ ((c & 7) << 4))) = pk;
        }
      }
      __syncthreads();
#pragma unroll 4
      for (int i = 0; i < 16; ++i) {
        const int G = i * 512 + t;
        const int e = G >> 5, m16 = G & 31;
        u16x8 v = *(const u16x8*)(Lb + e * 512 + ((m16 * 16) ^ ((e & 7) << 4)));
        *(u16x8*)(Co + (size_t)(lc0 + e) * MTOT + row0 + m16 * 8) = v;
      }
    }
  } else if constexpr (EPI == EPI_EXP) {
    // E = exp2(acc*scale); row sums from registers (shfl), coalesced E store.
#pragma unroll
    for (int mi = 0; mi < 8; ++mi)
#pragma unroll
      for (int ni = 0; ni < 4; ++ni)
#pragma unroll
        for (int j = 0; j < 4; ++j)
          acc[mi][ni][j] = exp2f(acc[mi][ni][j] * scale);

#pragma unroll
    for (int mi = 0; mi < 8; ++mi)
#pragma unroll
      for (int j = 0; j < 4; ++j) {
        float s = acc[mi][0][j] + acc[mi][1][j] + acc[mi][2][j] + acc[mi][3][j];
        s += __shfl_xor(s, 1);
        s += __shfl_xor(s, 2);
        s += __shfl_xor(s, 4);
        s += __shfl_xor(s, 8);
        if (fr == 0)
          atomicAdd(&lsum[(size_t)bz * SEQ + row0 + wm * 128 + mi * 16 + rb + j], s);
      }

#pragma unroll
    for (int mi = 0; mi < 8; ++mi) {
      const int r0 = wm * 128 + mi * 16 + rb;
#pragma unroll
      for (int ni = 0; ni < 4; ++ni) {
        const int c = wn * 64 + ni * 16 + fr;
#pragma unroll
        for (int j = 0; j < 4; ++j) {
          const int r = r0 + j;
          *(unsigned short*)(Lb + r * 512 + ((c * 2) ^ ((r & 7) << 4))) =
              f2bf(acc[mi][ni][j]);
        }
      }
    }
    __syncthreads();
    unsigned short* Co = (unsigned short*)C + (size_t)bz * (size_t)sC;
#pragma unroll 4
    for (int i = 0; i < 16; ++i) {
      const int G = i * 512 + t;
      const int r = G >> 5, c16 = G & 31;
      u16x8 v = *(const u16x8*)(Lb + r * 512 + ((c16 * 16) ^ ((r & 7) << 4)));
      *(u16x8*)(Co + (size_t)(row0 + r) * (size_t)ldc + col0 + c16 * 8) = v;
    }
  } else {  // EPI_PV: fp32 out / lsum[row], two 128-row halves through LDS
    float* Co = (float*)C + (size_t)bz * (size_t)sC;
#pragma unroll
    for (int h = 0; h < 2; ++h) {
      if (h) __syncthreads();
      if (wm == h) {
#pragma unroll
        for (int mi = 0; mi < 8; ++mi) {
          const int r0 = mi * 16 + rb;
#pragma unroll
          for (int ni = 0; ni < 4; ++ni) {
            const int c = wn * 64 + ni * 16 + fr;
#pragma unroll
            for (int j = 0; j < 4; ++j) {
              const int r = r0 + j;
              *(float*)(Lb + r * 1024 + ((c * 4) ^ ((r & 7) << 4))) = acc[mi][ni][j];
            }
          }
        }
      }
      __syncthreads();
#pragma unroll 4
      for (int i = 0; i < 16; ++i) {
        const int G = i * 512 + t;
        const int r = G >> 6, c4 = G & 63;
        f32x4 v = *(const f32x4*)(Lb + r * 1024 + ((c4 * 16) ^ ((r & 7) << 4)));
        const size_t grow = (size_t)row0 + h * 128 + r;
        const float inv = 1.0f / lsum[(size_t)bz * SEQ + grow];
        v *= inv;
        *(f32x4*)(Co + grow * (size_t)ldc + col0 + c4 * 4) = v;
      }
    }
  }
}

// ---------------- wrappers: every GEMM dispatch = 256 blocks (1 round/CU) ----------------
__global__ __launch_bounds__(512, 2) void gemm_qkv(
    const unsigned short* __restrict__ A, const unsigned short* __restrict__ B,
    unsigned short* __restrict__ C, const float* __restrict__ bcat) {
  // 256 blocks: row band (64) x col-tile c (4); each does Q,K,V at (row,c).
  const int row = (int)blockIdx.x;   // 0..63
  const int c   = (int)blockIdx.y;   // 0..3
#pragma unroll 1
  for (int which = 0; which < 3; ++which)
    gemm_body<EPI_QKV>(A, B, C, bcat, nullptr, DIM, DIM, DIM, DIM, 1.f,
                       row * 256, which * 1024 + c * 256, 0, 0, 0, 0);
}

__global__ __launch_bounds__(512, 2) void gemm_exp(
    const unsigned short* __restrict__ A, const unsigned short* __restrict__ B,
    unsigned short* __restrict__ C, float* __restrict__ lsum, int zoff) {
  // 256 blocks: row (16) x colpair (8) x batch (2); each does 2 col-tiles.
  const int row = (int)blockIdx.x;           // 0..15
  const int cp  = (int)blockIdx.y;           // 0..7
  const int bz  = (int)blockIdx.z + zoff;    // batch
#pragma unroll 1
  for (int cc = 0; cc < 2; ++cc)
    gemm_body<EPI_EXP>(A, B, C, nullptr, lsum, DIM, DIM, DIM, SEQ, 0.04508422f,
                       row * 256, (cp * 2 + cc) * 256, bz,
                       (long)SEQ * DIM, (long)SEQ * DIM, (long)SEQ * SEQ);
}

__global__ __launch_bounds__(512, 2) void gemm_pv(
    const unsigned short* __restrict__ A, const unsigned short* __restrict__ B,
    float* __restrict__ C, float* __restrict__ lsum) {
  // 256 blocks, XCD-swizzled: each XCD gets 8 row-tiles x 4 col-tiles
  const int flat = (int)blockIdx.x +
                   (int)gridDim.x * ((int)blockIdx.y + (int)gridDim.y * (int)blockIdx.z);
  const int nf  = (flat & 7) * 32 + (flat >> 3);   // bijective, 256 = 8 x 32
  const int b   = nf >> 6;
  const int rc  = nf & 63;
  const int row = rc >> 2, col = rc & 3;
  gemm_body<EPI_PV>(A, B, C, nullptr, lsum, SEQ, SEQ, MTOT, DIM, 1.f,
                    row * 256, col * 256, b,
                    (long)SEQ * SEQ, (long)SEQ, (long)SEQ * DIM);
}

extern "C" void kernel_launch(void* const* d_in, const int* in_sizes, int n_in,
                              void* d_out, int out_size, void* d_ws, size_t ws_size,
                              hipStream_t stream) {
  (void)in_sizes; (void)n_in; (void)out_size; (void)ws_size;
  const float* x  = (const float*)d_in[0];
  const float* Wq = (const float*)d_in[1];
  const float* bq = (const float*)d_in[2];
  const float* Wk = (const float*)d_in[3];
  const float* bk = (const float*)d_in[4];
  const float* Wv = (const float*)d_in[5];
  const float* bv = (const float*)d_in[6];
  float* out = (float*)d_out;

  const size_t SALL = (size_t)NB * SEQ * SEQ;
  unsigned short* Q  = (unsigned short*)d_ws;
  unsigned short* Km = Q + EL;
  unsigned short* VT = Km + EL;                  // transposed: VT[e][b*SEQ+s]
  unsigned short* Sb = VT + EL;                  // E = exp(S/32), unnormalized
  unsigned short* WT = Sb + SALL;                // [3072][1024] = WqT|WkT|WvT
  float*          l  = (float*)(WT + (size_t)3 * DIM * DIM);   // [MTOT] row sums
  float*          bc = l + MTOT;                 // bcat[3072]
  unsigned short* xb = Sb;                       // x_bf16 overlaps E (dead after proj)

  // prep (x cvt + lsum zero + bias) and W transposes in one dispatch
  prep_all<<<dim3(EL / 1024 + 3072), dim3(256), 0, stream>>>(
      x, xb, Wq, Wk, Wv, WT, bq, bk, bv, bc, l);

  // fused QKV projection: 256 blocks x 3 sequential col-loops
  gemm_qkv<<<dim3(64, 4), 512, 0, stream>>>(xb, WT, Q, bc);

  // E = exp(QK^T/32) + row sums: 2 dispatches x 256 blocks x 2 col-tiles
  gemm_exp<<<dim3(16, 8, 2), 512, 0, stream>>>(Q, Km, Sb, l, 0);
  gemm_exp<<<dim3(16, 8, 2), 512, 0, stream>>>(Q, Km, Sb, l, 2);

  // O = (E · V) / l  (fp32 out), XCD-swizzled grid
  gemm_pv<<<dim3(4, 16, 4), 512, 0, stream>>>(Sb, VT, out, l);
}

// Round 12
// 431.990 us; speedup vs baseline: 1.0938x; 1.0938x over previous
//
#include <hip/hip_runtime.h>
#include <hip/hip_bf16.h>
#include <cstdint>

#define SEQ 4096
#define NB 4
#define DIM 1024
#define MTOT (NB * SEQ)   // 16384
constexpr size_t EL = (size_t)MTOT * DIM;

using u16x8  = __attribute__((ext_vector_type(8))) unsigned short;
using bf16x8 = __attribute__((ext_vector_type(8))) __bf16;
using f32x4  = __attribute__((ext_vector_type(4))) float;

__device__ __forceinline__ unsigned short f2bf(float f) {
  return __builtin_bit_cast(unsigned short, __float2bfloat16(f));
}

__device__ __forceinline__ void gload16(const void* g, void* l) {
  __builtin_amdgcn_global_load_lds(
      (const __attribute__((address_space(1))) unsigned int*)g,
      (__attribute__((address_space(3))) unsigned int*)l, 16, 0, 0);
}
__device__ __forceinline__ void stage_half(const unsigned short* gsrc, size_t ld,
                                           unsigned short* ldst) {
  gload16(gsrc, ldst);
  gload16(gsrc + 64 * ld, ldst + 64 * 64);
}

#define BAR()   __builtin_amdgcn_s_barrier()
#define FENCE() asm volatile("" ::: "memory")

// Bias algebra (exact): S = (xWq+bq)(xWk+bk)^T = [x(WqWk^T) + bq·Wk^T·? ...]
//   A2[q,e] = Σ_d (xWq+bq)[q,d]·Wk[e,d]   (projection with column-bias bq·Wk^T)
//   S[q,k]  = A2[q,:]·x[k,:] + (Q_full[q,:]·bk)   — the bk term is constant per
//   row q → cancels exactly in softmax. So softmax(S) = softmax(A2·x^T).

// ------- prep: x cvt, lsum zero, bc=[0|bv], Wq/Wk plain cvt -------
#define NXB ((int)(EL / 1024))
__global__ __launch_bounds__(256) void prep(const float* __restrict__ x,
                                            unsigned short* __restrict__ xb,
                                            const float* __restrict__ Wq,
                                            const float* __restrict__ Wk,
                                            unsigned short* __restrict__ Wq_b,
                                            unsigned short* __restrict__ Wk_b,
                                            const float* __restrict__ bv,
                                            float* __restrict__ bc,
                                            float* __restrict__ l) {
  const int bid = (int)blockIdx.x;
  const int t = threadIdx.x;
  if (bid < NXB) {
    const size_t gid = (size_t)bid * 256 + t;
    const size_t i = gid * 4;
    float4 v = *(const float4*)(x + i);
    ushort4 o;
    o.x = f2bf(v.x); o.y = f2bf(v.y); o.z = f2bf(v.z); o.w = f2bf(v.w);
    *(ushort4*)(xb + i) = o;
    if (gid < MTOT) l[gid] = 0.f;
    if (gid < 2 * DIM) bc[gid] = gid < DIM ? 0.f : bv[gid - DIM];
  } else {
    const int wb = bid - NXB;              // 0..2047
    const int z = wb >> 10;                // 0=Wq 1=Wk
    const float* W = z ? Wk : Wq;
    unsigned short* O = z ? Wk_b : Wq_b;
    const size_t i = ((size_t)(wb & 1023) * 1024) + (size_t)t * 4;
    float4 v = *(const float4*)(W + i);
    ushort4 o;
    o.x = f2bf(v.x); o.y = f2bf(v.y); o.z = f2bf(v.z); o.w = f2bf(v.w);
    *(ushort4*)(O + i) = o;
  }
}

// ------- bq·Wk^T[e] (fp32, exact-ish) -> bc[0..1023] -------
__global__ __launch_bounds__(256) void bias_proj(const float* __restrict__ bq,
                                                 const float* __restrict__ Wk,
                                                 float* __restrict__ bc) {
  const int e = blockIdx.x * 256 + threadIdx.x;   // 0..1023
  float s = 0.f;
#pragma unroll 4
  for (int d = 0; d < DIM; ++d) s += bq[d] * Wk[(size_t)e * DIM + d];
  bc[e] = s;
}

// ------- Wv fp32 -> WvT bf16 (transpose) -------
__global__ __launch_bounds__(256) void transpose_w(const float* __restrict__ W,
                                                   unsigned short* __restrict__ WT) {
  __shared__ float tile[32][33];
  const int tx = threadIdx.x, ty = threadIdx.y;
  const int d0 = blockIdx.y * 32, e0 = blockIdx.x * 32;
#pragma unroll
  for (int j = 0; j < 32; j += 8)
    tile[ty + j][tx] = W[(size_t)(d0 + ty + j) * DIM + e0 + tx];
  __syncthreads();
#pragma unroll
  for (int j = 0; j < 32; j += 8)
    WT[(size_t)(e0 + ty + j) * DIM + d0 + tx] = f2bf(tile[tx][ty + j]);
}

// ============ small 128x128 BT-GEMM (R1-verified structure): MT = Wk_b·Wq_b^T ============
__global__ __launch_bounds__(256) void gemm_mt(
    const unsigned short* __restrict__ A, const unsigned short* __restrict__ B,
    unsigned short* __restrict__ C) {
  __shared__ unsigned short As[128 * 32];
  __shared__ unsigned short Bs[128 * 32];
  const int t = threadIdx.x;
  const int lane = t & 63;
  const int wave = t >> 6;
  const size_t row0 = (size_t)blockIdx.x * 128;
  const size_t col0 = (size_t)blockIdx.y * 128;
  const int wm = (wave >> 1) * 64;
  const int wn = (wave & 1) * 64;
  const int fr = lane & 15;
  const int fk = (lane >> 4) * 8;

  f32x4 acc[4][4];
  const f32x4 z4 = {0.f, 0.f, 0.f, 0.f};
#pragma unroll
  for (int i = 0; i < 4; ++i)
#pragma unroll
    for (int j = 0; j < 4; ++j) acc[i][j] = z4;

  const int srow = t >> 2;
  const int sseg = (t & 3) * 8;
  const unsigned short* gA = A + (row0 + srow) * (size_t)DIM + sseg;
  const unsigned short* gB = B + (col0 + srow) * (size_t)DIM + sseg;
  unsigned short* lA = As + wave * 512;
  unsigned short* lB = Bs + wave * 512;
  const size_t a64 = (size_t)64 * DIM;

  for (int k0 = 0; k0 < DIM; k0 += 32) {
    gload16(gA + k0, lA);
    gload16(gA + k0 + a64, lA + 2048);
    gload16(gB + k0, lB);
    gload16(gB + k0 + a64, lB + 2048);
    __syncthreads();
    bf16x8 af[4], bfr[4];
#pragma unroll
    for (int mi = 0; mi < 4; ++mi)
      af[mi] = *(const bf16x8*)(As + (wm + mi * 16 + fr) * 32 + fk);
#pragma unroll
    for (int ni = 0; ni < 4; ++ni)
      bfr[ni] = *(const bf16x8*)(Bs + (wn + ni * 16 + fr) * 32 + fk);
#pragma unroll
    for (int mi = 0; mi < 4; ++mi)
#pragma unroll
      for (int ni = 0; ni < 4; ++ni)
        acc[mi][ni] = __builtin_amdgcn_mfma_f32_16x16x32_bf16(af[mi], bfr[ni], acc[mi][ni], 0, 0, 0);
    __syncthreads();
  }

  const int rb = (lane >> 4) * 4;
#pragma unroll
  for (int ni = 0; ni < 4; ++ni) {
    size_t gc = col0 + wn + ni * 16 + fr;
#pragma unroll
    for (int mi = 0; mi < 4; ++mi) {
      size_t gr = row0 + wm + mi * 16 + rb;
#pragma unroll
      for (int j = 0; j < 4; ++j)
        C[(gr + j) * (size_t)DIM + gc] = f2bf(acc[mi][ni][j]);
    }
  }
}

// ============ 256x256 8-phase BT-GEMM body (R8-verified) ============
enum { EPI_QKV = 0, EPI_EXP = 1, EPI_PV = 2 };

template <int EPI>
__device__ __forceinline__ void gemm_body(
    const unsigned short* __restrict__ A, const unsigned short* __restrict__ B,
    void* __restrict__ C, const float* __restrict__ bias, float* __restrict__ lsum,
    int K, int lda, int ldb, int ldc, float scale,
    int row0, int col0, int bz, long sA, long sB, long sC) {
  __shared__ unsigned short sm[2][2][256 * 64];   // 128 KiB
  const int t    = threadIdx.x;
  const int lane = t & 63;
  const int wave = t >> 6;
  const int wm   = wave >> 2;
  const int wn   = wave & 3;
  const int fr   = lane & 15;
  const int g    = lane >> 4;
  const int xr   = (fr & 7) << 4;

  const unsigned short* Ab = A + (size_t)bz * (size_t)sA;
  const unsigned short* Bb = B + (size_t)bz * (size_t)sB;

  const int srow = t >> 3;
  const int scol = ((((t & 7) << 4) ^ ((srow & 7) << 4)) >> 1);
  const unsigned short* gA = Ab + (size_t)(row0 + srow) * (size_t)lda + scol;
  const unsigned short* gB = Bb + (size_t)(col0 + srow) * (size_t)ldb + scol;

  const int arow = wm * 128 + fr;
  const int brow = wn * 64 + fr;
  const int c0 = (((g << 4)) ^ xr) >> 1;
  const int c1 = ((64 | (g << 4)) ^ xr) >> 1;

  f32x4 acc[8][4];
  const f32x4 z4 = {0.f, 0.f, 0.f, 0.f};
#pragma unroll
  for (int i = 0; i < 8; ++i)
#pragma unroll
    for (int j = 0; j < 4; ++j) acc[i][j] = z4;

  const int nt = K >> 6;

  stage_half(gA, lda, &sm[0][0][wave * 512]);
  stage_half(gA + 128 * (size_t)lda, lda, &sm[0][0][8192 + wave * 512]);
  stage_half(gB, ldb, &sm[0][1][wave * 512]);
  stage_half(gB + 128 * (size_t)ldb, ldb, &sm[0][1][8192 + wave * 512]);
  if (nt > 1) {
    stage_half(gB + 64, ldb, &sm[1][1][wave * 512]);
    stage_half(gB + 128 * (size_t)ldb + 64, ldb, &sm[1][1][8192 + wave * 512]);
    stage_half(gA + 64, lda, &sm[1][0][wave * 512]);
    asm volatile("s_waitcnt vmcnt(6)" ::: "memory");
  } else {
    asm volatile("s_waitcnt vmcnt(0)" ::: "memory");
  }
  BAR(); FENCE();

  bf16x8 a0[4][2], a1[4][2], b0[2][2], b1[2][2];

  for (int kt = 0; kt < nt; ++kt) {
    const int p = kt & 1;
    const unsigned short* As  = sm[p][0];
    const unsigned short* Bs2 = sm[p][1];

    // P1: read A0-3 + B0-1 (12), stage T(kt+1).A-hi
#pragma unroll
    for (int mi = 0; mi < 4; ++mi) {
      a0[mi][0] = *(const bf16x8*)(As + (arow + mi * 16) * 64 + c0);
      a0[mi][1] = *(const bf16x8*)(As + (arow + mi * 16) * 64 + c1);
    }
#pragma unroll
    for (int ni = 0; ni < 2; ++ni) {
      b0[ni][0] = *(const bf16x8*)(Bs2 + (brow + ni * 16) * 64 + c0);
      b0[ni][1] = *(const bf16x8*)(Bs2 + (brow + ni * 16) * 64 + c1);
    }
    if (kt + 1 < nt)
      stage_half(gA + 128 * (size_t)lda + (size_t)(kt + 1) * 64, lda,
                 &sm[p ^ 1][0][8192 + wave * 512]);
    FENCE(); BAR(); FENCE();
    __builtin_amdgcn_s_setprio(1);
#pragma unroll
    for (int mi = 0; mi < 4; ++mi)
#pragma unroll
      for (int ni = 0; ni < 2; ++ni) {
        acc[mi][ni] = __builtin_amdgcn_mfma_f32_16x16x32_bf16(a0[mi][0], b0[ni][0], acc[mi][ni], 0, 0, 0);
        acc[mi][ni] = __builtin_amdgcn_mfma_f32_16x16x32_bf16(a0[mi][1], b0[ni][1], acc[mi][ni], 0, 0, 0);
      }
    __builtin_amdgcn_s_setprio(0);
    FENCE(); BAR(); FENCE();

    // P2: read B2-3 (4)
#pragma unroll
    for (int ni = 0; ni < 2; ++ni) {
      b1[ni][0] = *(const bf16x8*)(Bs2 + (brow + (ni + 2) * 16) * 64 + c0);
      b1[ni][1] = *(const bf16x8*)(Bs2 + (brow + (ni + 2) * 16) * 64 + c1);
    }
    FENCE(); BAR(); FENCE();
    __builtin_amdgcn_s_setprio(1);
#pragma unroll
    for (int mi = 0; mi < 4; ++mi)
#pragma unroll
      for (int ni = 0; ni < 2; ++ni) {
        acc[mi][ni + 2] = __builtin_amdgcn_mfma_f32_16x16x32_bf16(a0[mi][0], b1[ni][0], acc[mi][ni + 2], 0, 0, 0);
        acc[mi][ni + 2] = __builtin_amdgcn_mfma_f32_16x16x32_bf16(a0[mi][1], b1[ni][1], acc[mi][ni + 2], 0, 0, 0);
      }
    __builtin_amdgcn_s_setprio(0);
    FENCE(); BAR(); FENCE();

    // P3: read A4-7 (8), stage T(kt+2).B-lo
#pragma unroll
    for (int mi = 0; mi < 4; ++mi) {
      a1[mi][0] = *(const bf16x8*)(As + (arow + (mi + 4) * 16) * 64 + c0);
      a1[mi][1] = *(const bf16x8*)(As + (arow + (mi + 4) * 16) * 64 + c1);
    }
    if (kt + 2 < nt)
      stage_half(gB + (size_t)(kt + 2) * 64, ldb, &sm[p][1][wave * 512]);
    FENCE(); BAR(); FENCE();
    __builtin_amdgcn_s_setprio(1);
#pragma unroll
    for (int mi = 0; mi < 4; ++mi)
#pragma unroll
      for (int ni = 0; ni < 2; ++ni) {
        acc[mi + 4][ni] = __builtin_amdgcn_mfma_f32_16x16x32_bf16(a1[mi][0], b0[ni][0], acc[mi + 4][ni], 0, 0, 0);
        acc[mi + 4][ni] = __builtin_amdgcn_mfma_f32_16x16x32_bf16(a1[mi][1], b0[ni][1], acc[mi + 4][ni], 0, 0, 0);
      }
    __builtin_amdgcn_s_setprio(0);
    FENCE(); BAR(); FENCE();

    // P4: stage T(kt+2).{B-hi,A-lo}; counted vmcnt; MFMA q4
    if (kt + 2 < nt) {
      stage_half(gB + 128 * (size_t)ldb + (size_t)(kt + 2) * 64, ldb,
                 &sm[p][1][8192 + wave * 512]);
      stage_half(gA + (size_t)(kt + 2) * 64, lda, &sm[p][0][wave * 512]);
      asm volatile("s_waitcnt vmcnt(6)" ::: "memory");
    } else {
      asm volatile("s_waitcnt vmcnt(0)" ::: "memory");
    }
    FENCE(); BAR(); FENCE();
    __builtin_amdgcn_s_setprio(1);
#pragma unroll
    for (int mi = 0; mi < 4; ++mi)
#pragma unroll
      for (int ni = 0; ni < 2; ++ni) {
        acc[mi + 4][ni + 2] = __builtin_amdgcn_mfma_f32_16x16x32_bf16(a1[mi][0], b1[ni][0], acc[mi + 4][ni + 2], 0, 0, 0);
        acc[mi + 4][ni + 2] = __builtin_amdgcn_mfma_f32_16x16x32_bf16(a1[mi][1], b1[ni][1], acc[mi + 4][ni + 2], 0, 0, 0);
      }
    __builtin_amdgcn_s_setprio(0);
    FENCE(); BAR(); FENCE();
  }

  // ===================== LDS-staged coalesced epilogues =====================
  char* Lb = (char*)&sm[0][0][0];
  const int rb = (lane >> 4) * 4;

  if constexpr (EPI == EPI_QKV) {
    const int which = col0 >> 10;            // 0 = A2 (xM+biasproj), 1 = V
    const int lc0   = col0 & 1023;
    unsigned short* Co = (unsigned short*)C + (size_t)which * EL;
    if (which < 1) {
      float bb[4];
#pragma unroll
      for (int ni = 0; ni < 4; ++ni) bb[ni] = bias[col0 + wn * 64 + ni * 16 + fr];
#pragma unroll
      for (int mi = 0; mi < 8; ++mi) {
        const int r0 = wm * 128 + mi * 16 + rb;
#pragma unroll
        for (int ni = 0; ni < 4; ++ni) {
          const int c = wn * 64 + ni * 16 + fr;
#pragma unroll
          for (int j = 0; j < 4; ++j) {
            const int r = r0 + j;
            *(unsigned short*)(Lb + r * 512 + ((c * 2) ^ ((r & 7) << 4))) =
                f2bf(acc[mi][ni][j] + bb[ni]);
          }
        }
      }
      __syncthreads();
#pragma unroll 4
      for (int i = 0; i < 16; ++i) {
        const int G = i * 512 + t;
        const int r = G >> 5, c16 = G & 31;
        u16x8 v = *(const u16x8*)(Lb + r * 512 + ((c16 * 16) ^ ((r & 7) << 4)));
        *(u16x8*)(Co + (size_t)(row0 + r) * DIM + lc0 + c16 * 8) = v;
      }
    } else {
      // V: store transposed through col-major LDS tile
#pragma unroll
      for (int ni = 0; ni < 4; ++ni) {
        const int c = wn * 64 + ni * 16 + fr;
        const float bb = bias[col0 + c];
#pragma unroll
        for (int mi = 0; mi < 8; ++mi) {
          const int r0 = wm * 128 + mi * 16 + rb;
          ushort4 pk;
          pk.x = f2bf(acc[mi][ni][0] + bb);
          pk.y = f2bf(acc[mi][ni][1] + bb);
          pk.z = f2bf(acc[mi][ni][2] + bb);
          pk.w = f2bf(acc[mi][ni][3] + bb);
          *(ushort4*)(Lb + c * 512 + ((r0 * 2) ^ ((c & 7) << 4))) = pk;
        }
      }
      __syncthreads();
#pragma unroll 4
      for (int i = 0; i < 16; ++i) {
        const int G = i * 512 + t;
        const int e = G >> 5, m16 = G & 31;
        u16x8 v = *(const u16x8*)(Lb + e * 512 + ((m16 * 16) ^ ((e & 7) << 4)));
        *(u16x8*)(Co + (size_t)(lc0 + e) * MTOT + row0 + m16 * 8) = v;
      }
    }
  } else if constexpr (EPI == EPI_EXP) {
#pragma unroll
    for (int mi = 0; mi < 8; ++mi)
#pragma unroll
      for (int ni = 0; ni < 4; ++ni)
#pragma unroll
        for (int j = 0; j < 4; ++j)
          acc[mi][ni][j] = exp2f(acc[mi][ni][j] * scale);

#pragma unroll
    for (int mi = 0; mi < 8; ++mi)
#pragma unroll
      for (int j = 0; j < 4; ++j) {
        float s = acc[mi][0][j] + acc[mi][1][j] + acc[mi][2][j] + acc[mi][3][j];
        s += __shfl_xor(s, 1);
        s += __shfl_xor(s, 2);
        s += __shfl_xor(s, 4);
        s += __shfl_xor(s, 8);
        if (fr == 0)
          atomicAdd(&lsum[(size_t)bz * SEQ + row0 + wm * 128 + mi * 16 + rb + j], s);
      }

#pragma unroll
    for (int mi = 0; mi < 8; ++mi) {
      const int r0 = wm * 128 + mi * 16 + rb;
#pragma unroll
      for (int ni = 0; ni < 4; ++ni) {
        const int c = wn * 64 + ni * 16 + fr;
#pragma unroll
        for (int j = 0; j < 4; ++j) {
          const int r = r0 + j;
          *(unsigned short*)(Lb + r * 512 + ((c * 2) ^ ((r & 7) << 4))) =
              f2bf(acc[mi][ni][j]);
        }
      }
    }
    __syncthreads();
    unsigned short* Co = (unsigned short*)C + (size_t)bz * (size_t)sC;
#pragma unroll 4
    for (int i = 0; i < 16; ++i) {
      const int G = i * 512 + t;
      const int r = G >> 5, c16 = G & 31;
      u16x8 v = *(const u16x8*)(Lb + r * 512 + ((c16 * 16) ^ ((r & 7) << 4)));
      *(u16x8*)(Co + (size_t)(row0 + r) * (size_t)ldc + col0 + c16 * 8) = v;
    }
  } else {  // EPI_PV
    float* Co = (float*)C + (size_t)bz * (size_t)sC;
#pragma unroll
    for (int h = 0; h < 2; ++h) {
      if (h) __syncthreads();
      if (wm == h) {
#pragma unroll
        for (int mi = 0; mi < 8; ++mi) {
          const int r0 = mi * 16 + rb;
#pragma unroll
          for (int ni = 0; ni < 4; ++ni) {
            const int c = wn * 64 + ni * 16 + fr;
#pragma unroll
            for (int j = 0; j < 4; ++j) {
              const int r = r0 + j;
              *(float*)(Lb + r * 1024 + ((c * 4) ^ ((r & 7) << 4))) = acc[mi][ni][j];
            }
          }
        }
      }
      __syncthreads();
#pragma unroll 4
      for (int i = 0; i < 16; ++i) {
        const int G = i * 512 + t;
        const int r = G >> 6, c4 = G & 63;
        f32x4 v = *(const f32x4*)(Lb + r * 1024 + ((c4 * 16) ^ ((r & 7) << 4)));
        const size_t grow = (size_t)row0 + h * 128 + r;
        const float inv = 1.0f / lsum[(size_t)bz * SEQ + grow];
        v *= inv;
        *(f32x4*)(Co + grow * (size_t)ldc + col0 + c4 * 4) = v;
      }
    }
  }
}

// ---------------- wrappers ----------------
__global__ __launch_bounds__(512, 2) void gemm_qkv(
    const unsigned short* __restrict__ A, const unsigned short* __restrict__ B,
    unsigned short* __restrict__ C, const float* __restrict__ bcat) {
  const int flat = (int)blockIdx.x + 64 * (int)blockIdx.y;   // 0..511
  const int xcd = flat & 7, j = flat >> 3;                   // j 0..63
  const int row = xcd * 8 + (j & 7);
  const int col = j >> 3;                                    // 0..7
  gemm_body<EPI_QKV>(A, B, C, bcat, nullptr, DIM, DIM, DIM, DIM, 1.f,
                     row * 256, col * 256, 0, 0, 0, 0);
}

__global__ __launch_bounds__(512, 2) void gemm_exp(
    const unsigned short* __restrict__ A, const unsigned short* __restrict__ B,
    unsigned short* __restrict__ C, float* __restrict__ lsum) {
  const int flat = (int)blockIdx.x +
                   (int)gridDim.x * ((int)blockIdx.y + (int)gridDim.y * (int)blockIdx.z);
  const int xcd = flat & 7, j = flat >> 3;
  const int bz  = (xcd >> 2) * 2 + (j >> 6);
  const int jj  = j & 63;
  const int row = (xcd & 3) * 4 + (jj & 3);
  const int col = jj >> 2;
  gemm_body<EPI_EXP>(A, B, C, nullptr, lsum, DIM, DIM, DIM, SEQ, 0.04508422f,
                     row * 256, col * 256, bz,
                     (long)SEQ * DIM, (long)SEQ * DIM, (long)SEQ * SEQ);
}

__global__ __launch_bounds__(512, 2) void gemm_pv(
    const unsigned short* __restrict__ A, const unsigned short* __restrict__ B,
    float* __restrict__ C, float* __restrict__ lsum) {
  const int flat = (int)blockIdx.x +
                   (int)gridDim.x * ((int)blockIdx.y + (int)gridDim.y * (int)blockIdx.z);
  const int nf  = (flat & 7) * 32 + (flat >> 3);
  const int b   = nf >> 6;
  const int rc  = nf & 63;
  const int row = rc >> 2, col = rc & 3;
  gemm_body<EPI_PV>(A, B, C, nullptr, lsum, SEQ, SEQ, MTOT, DIM, 1.f,
                    row * 256, col * 256, b,
                    (long)SEQ * SEQ, (long)SEQ, (long)SEQ * DIM);
}

extern "C" void kernel_launch(void* const* d_in, const int* in_sizes, int n_in,
                              void* d_out, int out_size, void* d_ws, size_t ws_size,
                              hipStream_t stream) {
  (void)in_sizes; (void)n_in; (void)out_size; (void)ws_size;
  const float* x  = (const float*)d_in[0];
  const float* Wq = (const float*)d_in[1];
  const float* bq = (const float*)d_in[2];
  const float* Wk = (const float*)d_in[3];
  const float* Wv = (const float*)d_in[5];
  const float* bv = (const float*)d_in[6];
  float* out = (float*)d_out;

  const size_t SALL = (size_t)NB * SEQ * SEQ;
  unsigned short* Q    = (unsigned short*)d_ws;      // A2 buffer [MTOT][1024]
  unsigned short* VT   = Q + EL;                     // V^T bf16 [DIM][MTOT]
  unsigned short* xb   = VT + EL;                    // x bf16 (exp's B operand)
  unsigned short* Sb   = xb + EL;                    // E bf16 [NB][SEQ][SEQ]
  unsigned short* MT   = Sb;                         // carved (dead after proj)
  unsigned short* WvT  = MT + (size_t)DIM * DIM;
  unsigned short* Wq_b = WvT + (size_t)DIM * DIM;
  unsigned short* Wk_b = Wq_b + (size_t)DIM * DIM;
  float*          l    = (float*)(Sb + SALL);
  float*          bc   = l + MTOT;                   // [bq·Wk^T | bv]

  prep<<<dim3(NXB + 2048), dim3(256), 0, stream>>>(x, xb, Wq, Wk, Wq_b, Wk_b,
                                                   bv, bc, l);
  transpose_w<<<dim3(32, 32), dim3(32, 8), 0, stream>>>(Wv, WvT);
  bias_proj<<<dim3(4), dim3(256), 0, stream>>>(bq, Wk, bc);
  // MT[e,d] = Σ_f Wk[e,f]·Wq[d,f]  →  A2 = x·MT^T (+ bc) = (xWq+bq)·Wk^T − bq-part via bc
  gemm_mt<<<dim3(8, 8), 256, 0, stream>>>(Wk_b, Wq_b, MT);

  // proj: A2 (bias bq·Wk^T) + V^T (bias bv); B = [MT | WvT] contiguous
  gemm_qkv<<<dim3(64, 8), 512, 0, stream>>>(xb, MT, Q, bc);

  // E = exp2(S·log2e/32), S = A2·x^T (bk row-shift cancels in softmax)
  gemm_exp<<<dim3(SEQ / 256, SEQ / 256, NB), 512, 0, stream>>>(Q, xb, Sb, l);

  // O = (E·V)/l
  gemm_pv<<<dim3(4, 16, 4), 512, 0, stream>>>(Sb, VT, out, l);
}

// Round 13
// 422.679 us; speedup vs baseline: 1.1179x; 1.0220x over previous
//
#include <hip/hip_runtime.h>
#include <hip/hip_bf16.h>
#include <cstdint>

#define SEQ 4096
#define NB 4
#define DIM 1024
#define MTOT (NB * SEQ)   // 16384
constexpr size_t EL = (size_t)MTOT * DIM;

using u16x8  = __attribute__((ext_vector_type(8))) unsigned short;
using bf16x8 = __attribute__((ext_vector_type(8))) __bf16;
using f32x4  = __attribute__((ext_vector_type(4))) float;

__device__ __forceinline__ unsigned short f2bf(float f) {
  return __builtin_bit_cast(unsigned short, __float2bfloat16(f));  // native RNE
}

__device__ __forceinline__ void gload16(const unsigned short* g, unsigned short* l) {
  __builtin_amdgcn_global_load_lds(
      (const __attribute__((address_space(1))) unsigned int*)g,
      (__attribute__((address_space(3))) unsigned int*)l, 16, 0, 0);
}
__device__ __forceinline__ void stage_half(const unsigned short* gsrc, size_t ld,
                                           unsigned short* ldst) {
  gload16(gsrc, ldst);
  gload16(gsrc + 64 * ld, ldst + 64 * 64);
}

#define BAR()   __builtin_amdgcn_s_barrier()
#define FENCE() asm volatile("" ::: "memory")

// ------- prep: x fp32->bf16, bias concat, lsum zero -------
__global__ __launch_bounds__(256) void prep(const float* __restrict__ x,
                                            unsigned short* __restrict__ xb,
                                            const float* __restrict__ bq,
                                            const float* __restrict__ bk,
                                            const float* __restrict__ bv,
                                            float* __restrict__ bc,
                                            float* __restrict__ l) {
  const size_t gid = (size_t)blockIdx.x * 256 + threadIdx.x;
  const size_t i = gid * 4;
  float4 v = *(const float4*)(x + i);
  ushort4 o;
  o.x = f2bf(v.x); o.y = f2bf(v.y); o.z = f2bf(v.z); o.w = f2bf(v.w);
  *(ushort4*)(xb + i) = o;
  if (gid < MTOT) l[gid] = 0.f;
  if (gid < 3 * DIM)
    bc[gid] = gid < DIM ? bq[gid] : gid < 2 * DIM ? bk[gid - DIM] : bv[gid - 2 * DIM];
}

// ------- W fp32 [1024][1024] -> WT bf16, 3 matrices via blockIdx.z -------
__global__ __launch_bounds__(256) void transpose_w3(const float* __restrict__ Wq,
                                                    const float* __restrict__ Wk,
                                                    const float* __restrict__ Wv,
                                                    unsigned short* __restrict__ WT) {
  const float* W = blockIdx.z == 0 ? Wq : blockIdx.z == 1 ? Wk : Wv;
  unsigned short* O = WT + (size_t)blockIdx.z * DIM * DIM;
  __shared__ float tile[32][33];
  const int tx = threadIdx.x, ty = threadIdx.y;
  const int d0 = blockIdx.y * 32, e0 = blockIdx.x * 32;
#pragma unroll
  for (int j = 0; j < 32; j += 8)
    tile[ty + j][tx] = W[(size_t)(d0 + ty + j) * DIM + e0 + tx];
  __syncthreads();
#pragma unroll
  for (int j = 0; j < 32; j += 8)
    O[(size_t)(e0 + ty + j) * DIM + d0 + tx] = f2bf(tile[tx][ty + j]);
}

// ============ 256x256 8-phase BT-GEMM body: C[M,N] = A[M,K] * B^T ============
// 512 thr = 8 waves (2M x 4N); wave tile 128x64; BK=64; LDS 128KiB (2 K-tile bufs).
// Epilogue output streams use NON-TEMPORAL stores: outputs are consumed by a
// LATER dispatch, so bypassing L2 preserves staging-panel residency (the
// measured exp bottleneck: 6.1 TB/s staging supply = L3-bound from L2 thrash).
enum { EPI_QKV = 0, EPI_EXP = 1, EPI_PV = 2 };

template <int EPI>
__device__ __forceinline__ void gemm_body(
    const unsigned short* __restrict__ A, const unsigned short* __restrict__ B,
    void* __restrict__ C, const float* __restrict__ bias, float* __restrict__ lsum,
    int K, int lda, int ldb, int ldc, float scale,
    int row0, int col0, int bz, long sA, long sB, long sC) {
  __shared__ unsigned short sm[2][2][256 * 64];   // 128 KiB
  const int t    = threadIdx.x;
  const int lane = t & 63;
  const int wave = t >> 6;
  const int wm   = wave >> 2;
  const int wn   = wave & 3;
  const int fr   = lane & 15;
  const int g    = lane >> 4;
  const int xr   = (fr & 7) << 4;

  const unsigned short* Ab = A + (size_t)bz * (size_t)sA;
  const unsigned short* Bb = B + (size_t)bz * (size_t)sB;

  const int srow = t >> 3;
  const int scol = ((((t & 7) << 4) ^ ((srow & 7) << 4)) >> 1);
  const unsigned short* gA = Ab + (size_t)(row0 + srow) * (size_t)lda + scol;
  const unsigned short* gB = Bb + (size_t)(col0 + srow) * (size_t)ldb + scol;

  const int arow = wm * 128 + fr;
  const int brow = wn * 64 + fr;
  const int c0 = (((g << 4)) ^ xr) >> 1;
  const int c1 = ((64 | (g << 4)) ^ xr) >> 1;

  f32x4 acc[8][4];
  const f32x4 z4 = {0.f, 0.f, 0.f, 0.f};
#pragma unroll
  for (int i = 0; i < 8; ++i)
#pragma unroll
    for (int j = 0; j < 4; ++j) acc[i][j] = z4;

  const int nt = K >> 6;

  stage_half(gA, lda, &sm[0][0][wave * 512]);
  stage_half(gA + 128 * (size_t)lda, lda, &sm[0][0][8192 + wave * 512]);
  stage_half(gB, ldb, &sm[0][1][wave * 512]);
  stage_half(gB + 128 * (size_t)ldb, ldb, &sm[0][1][8192 + wave * 512]);
  if (nt > 1) {
    stage_half(gB + 64, ldb, &sm[1][1][wave * 512]);
    stage_half(gB + 128 * (size_t)ldb + 64, ldb, &sm[1][1][8192 + wave * 512]);
    stage_half(gA + 64, lda, &sm[1][0][wave * 512]);
    asm volatile("s_waitcnt vmcnt(6)" ::: "memory");
  } else {
    asm volatile("s_waitcnt vmcnt(0)" ::: "memory");
  }
  BAR(); FENCE();

  bf16x8 a0[4][2], a1[4][2], b0[2][2], b1[2][2];

  for (int kt = 0; kt < nt; ++kt) {
    const int p = kt & 1;
    const unsigned short* As  = sm[p][0];
    const unsigned short* Bs2 = sm[p][1];

    // P1: read A0-3 + B0-1 (12), stage T(kt+1).A-hi
#pragma unroll
    for (int mi = 0; mi < 4; ++mi) {
      a0[mi][0] = *(const bf16x8*)(As + (arow + mi * 16) * 64 + c0);
      a0[mi][1] = *(const bf16x8*)(As + (arow + mi * 16) * 64 + c1);
    }
#pragma unroll
    for (int ni = 0; ni < 2; ++ni) {
      b0[ni][0] = *(const bf16x8*)(Bs2 + (brow + ni * 16) * 64 + c0);
      b0[ni][1] = *(const bf16x8*)(Bs2 + (brow + ni * 16) * 64 + c1);
    }
    if (kt + 1 < nt)
      stage_half(gA + 128 * (size_t)lda + (size_t)(kt + 1) * 64, lda,
                 &sm[p ^ 1][0][8192 + wave * 512]);
    FENCE(); BAR(); FENCE();
    __builtin_amdgcn_s_setprio(1);
#pragma unroll
    for (int mi = 0; mi < 4; ++mi)
#pragma unroll
      for (int ni = 0; ni < 2; ++ni) {
        acc[mi][ni] = __builtin_amdgcn_mfma_f32_16x16x32_bf16(a0[mi][0], b0[ni][0], acc[mi][ni], 0, 0, 0);
        acc[mi][ni] = __builtin_amdgcn_mfma_f32_16x16x32_bf16(a0[mi][1], b0[ni][1], acc[mi][ni], 0, 0, 0);
      }
    __builtin_amdgcn_s_setprio(0);
    FENCE(); BAR(); FENCE();

    // P2: read B2-3 (4)
#pragma unroll
    for (int ni = 0; ni < 2; ++ni) {
      b1[ni][0] = *(const bf16x8*)(Bs2 + (brow + (ni + 2) * 16) * 64 + c0);
      b1[ni][1] = *(const bf16x8*)(Bs2 + (brow + (ni + 2) * 16) * 64 + c1);
    }
    FENCE(); BAR(); FENCE();
    __builtin_amdgcn_s_setprio(1);
#pragma unroll
    for (int mi = 0; mi < 4; ++mi)
#pragma unroll
      for (int ni = 0; ni < 2; ++ni) {
        acc[mi][ni + 2] = __builtin_amdgcn_mfma_f32_16x16x32_bf16(a0[mi][0], b1[ni][0], acc[mi][ni + 2], 0, 0, 0);
        acc[mi][ni + 2] = __builtin_amdgcn_mfma_f32_16x16x32_bf16(a0[mi][1], b1[ni][1], acc[mi][ni + 2], 0, 0, 0);
      }
    __builtin_amdgcn_s_setprio(0);
    FENCE(); BAR(); FENCE();

    // P3: read A4-7 (8), stage T(kt+2).B-lo
#pragma unroll
    for (int mi = 0; mi < 4; ++mi) {
      a1[mi][0] = *(const bf16x8*)(As + (arow + (mi + 4) * 16) * 64 + c0);
      a1[mi][1] = *(const bf16x8*)(As + (arow + (mi + 4) * 16) * 64 + c1);
    }
    if (kt + 2 < nt)
      stage_half(gB + (size_t)(kt + 2) * 64, ldb, &sm[p][1][wave * 512]);
    FENCE(); BAR(); FENCE();
    __builtin_amdgcn_s_setprio(1);
#pragma unroll
    for (int mi = 0; mi < 4; ++mi)
#pragma unroll
      for (int ni = 0; ni < 2; ++ni) {
        acc[mi + 4][ni] = __builtin_amdgcn_mfma_f32_16x16x32_bf16(a1[mi][0], b0[ni][0], acc[mi + 4][ni], 0, 0, 0);
        acc[mi + 4][ni] = __builtin_amdgcn_mfma_f32_16x16x32_bf16(a1[mi][1], b0[ni][1], acc[mi + 4][ni], 0, 0, 0);
      }
    __builtin_amdgcn_s_setprio(0);
    FENCE(); BAR(); FENCE();

    // P4: stage T(kt+2).{B-hi,A-lo}; counted vmcnt; MFMA q4
    if (kt + 2 < nt) {
      stage_half(gB + 128 * (size_t)ldb + (size_t)(kt + 2) * 64, ldb,
                 &sm[p][1][8192 + wave * 512]);
      stage_half(gA + (size_t)(kt + 2) * 64, lda, &sm[p][0][wave * 512]);
      asm volatile("s_waitcnt vmcnt(6)" ::: "memory");
    } else {
      asm volatile("s_waitcnt vmcnt(0)" ::: "memory");
    }
    FENCE(); BAR(); FENCE();
    __builtin_amdgcn_s_setprio(1);
#pragma unroll
    for (int mi = 0; mi < 4; ++mi)
#pragma unroll
      for (int ni = 0; ni < 2; ++ni) {
        acc[mi + 4][ni + 2] = __builtin_amdgcn_mfma_f32_16x16x32_bf16(a1[mi][0], b1[ni][0], acc[mi + 4][ni + 2], 0, 0, 0);
        acc[mi + 4][ni + 2] = __builtin_amdgcn_mfma_f32_16x16x32_bf16(a1[mi][1], b1[ni][1], acc[mi + 4][ni + 2], 0, 0, 0);
      }
    __builtin_amdgcn_s_setprio(0);
    FENCE(); BAR(); FENCE();
  }

  // ===================== LDS-staged coalesced epilogues (nt stores) =====================
  char* Lb = (char*)&sm[0][0][0];
  const int rb = (lane >> 4) * 4;

  if constexpr (EPI == EPI_QKV) {
    const int which = col0 >> 10;            // 0=Q 1=K 2=V
    const int lc0   = col0 & 1023;
    unsigned short* Co = (unsigned short*)C + (size_t)which * EL;
    if (which < 2) {
      float bb[4];
#pragma unroll
      for (int ni = 0; ni < 4; ++ni) bb[ni] = bias[col0 + wn * 64 + ni * 16 + fr];
#pragma unroll
      for (int mi = 0; mi < 8; ++mi) {
        const int r0 = wm * 128 + mi * 16 + rb;
#pragma unroll
        for (int ni = 0; ni < 4; ++ni) {
          const int c = wn * 64 + ni * 16 + fr;
#pragma unroll
          for (int j = 0; j < 4; ++j) {
            const int r = r0 + j;
            *(unsigned short*)(Lb + r * 512 + ((c * 2) ^ ((r & 7) << 4))) =
                f2bf(acc[mi][ni][j] + bb[ni]);
          }
        }
      }
      __syncthreads();
#pragma unroll 4
      for (int i = 0; i < 16; ++i) {
        const int G = i * 512 + t;
        const int r = G >> 5, c16 = G & 31;
        u16x8 v = *(const u16x8*)(Lb + r * 512 + ((c16 * 16) ^ ((r & 7) << 4)));
        __builtin_nontemporal_store(v,
            (u16x8*)(Co + (size_t)(row0 + r) * DIM + lc0 + c16 * 8));
      }
    } else {
      // V: store transposed through col-major LDS tile
#pragma unroll
      for (int ni = 0; ni < 4; ++ni) {
        const int c = wn * 64 + ni * 16 + fr;
        const float bb = bias[col0 + c];
#pragma unroll
        for (int mi = 0; mi < 8; ++mi) {
          const int r0 = wm * 128 + mi * 16 + rb;
          ushort4 pk;
          pk.x = f2bf(acc[mi][ni][0] + bb);
          pk.y = f2bf(acc[mi][ni][1] + bb);
          pk.z = f2bf(acc[mi][ni][2] + bb);
          pk.w = f2bf(acc[mi][ni][3] + bb);
          *(ushort4*)(Lb + c * 512 + ((r0 * 2) ^ ((c & 7) << 4))) = pk;
        }
      }
      __syncthreads();
#pragma unroll 4
      for (int i = 0; i < 16; ++i) {
        const int G = i * 512 + t;
        const int e = G >> 5, m16 = G & 31;
        u16x8 v = *(const u16x8*)(Lb + e * 512 + ((m16 * 16) ^ ((e & 7) << 4)));
        __builtin_nontemporal_store(v,
            (u16x8*)(Co + (size_t)(lc0 + e) * MTOT + row0 + m16 * 8));
      }
    }
  } else if constexpr (EPI == EPI_EXP) {
    // E = exp2(acc*scale); row sums from registers (shfl), coalesced nt E store.
#pragma unroll
    for (int mi = 0; mi < 8; ++mi)
#pragma unroll
      for (int ni = 0; ni < 4; ++ni)
#pragma unroll
        for (int j = 0; j < 4; ++j)
          acc[mi][ni][j] = exp2f(acc[mi][ni][j] * scale);

#pragma unroll
    for (int mi = 0; mi < 8; ++mi)
#pragma unroll
      for (int j = 0; j < 4; ++j) {
        float s = acc[mi][0][j] + acc[mi][1][j] + acc[mi][2][j] + acc[mi][3][j];
        s += __shfl_xor(s, 1);
        s += __shfl_xor(s, 2);
        s += __shfl_xor(s, 4);
        s += __shfl_xor(s, 8);
        if (fr == 0)
          atomicAdd(&lsum[(size_t)bz * SEQ + row0 + wm * 128 + mi * 16 + rb + j], s);
      }

#pragma unroll
    for (int mi = 0; mi < 8; ++mi) {
      const int r0 = wm * 128 + mi * 16 + rb;
#pragma unroll
      for (int ni = 0; ni < 4; ++ni) {
        const int c = wn * 64 + ni * 16 + fr;
#pragma unroll
        for (int j = 0; j < 4; ++j) {
          const int r = r0 + j;
          *(unsigned short*)(Lb + r * 512 + ((c * 2) ^ ((r & 7) << 4))) =
              f2bf(acc[mi][ni][j]);
        }
      }
    }
    __syncthreads();
    unsigned short* Co = (unsigned short*)C + (size_t)bz * (size_t)sC;
#pragma unroll 4
    for (int i = 0; i < 16; ++i) {
      const int G = i * 512 + t;
      const int r = G >> 5, c16 = G & 31;
      u16x8 v = *(const u16x8*)(Lb + r * 512 + ((c16 * 16) ^ ((r & 7) << 4)));
      __builtin_nontemporal_store(v,
          (u16x8*)(Co + (size_t)(row0 + r) * (size_t)ldc + col0 + c16 * 8));
    }
  } else {  // EPI_PV: fp32 out / lsum[row], two 128-row halves through LDS
    float* Co = (float*)C + (size_t)bz * (size_t)sC;
#pragma unroll
    for (int h = 0; h < 2; ++h) {
      if (h) __syncthreads();
      if (wm == h) {
#pragma unroll
        for (int mi = 0; mi < 8; ++mi) {
          const int r0 = mi * 16 + rb;
#pragma unroll
          for (int ni = 0; ni < 4; ++ni) {
            const int c = wn * 64 + ni * 16 + fr;
#pragma unroll
            for (int j = 0; j < 4; ++j) {
              const int r = r0 + j;
              *(float*)(Lb + r * 1024 + ((c * 4) ^ ((r & 7) << 4))) = acc[mi][ni][j];
            }
          }
        }
      }
      __syncthreads();
#pragma unroll 4
      for (int i = 0; i < 16; ++i) {
        const int G = i * 512 + t;
        const int r = G >> 6, c4 = G & 63;
        f32x4 v = *(const f32x4*)(Lb + r * 1024 + ((c4 * 16) ^ ((r & 7) << 4)));
        const size_t grow = (size_t)row0 + h * 128 + r;
        const float inv = 1.0f / lsum[(size_t)bz * SEQ + grow];
        v *= inv;
        __builtin_nontemporal_store(v,
            (f32x4*)(Co + grow * (size_t)ldc + col0 + c4 * 4));
      }
    }
  }
}

// ---------------- wrappers with XCD-locality block remaps ----------------
__global__ __launch_bounds__(512, 2) void gemm_qkv(
    const unsigned short* __restrict__ A, const unsigned short* __restrict__ B,
    unsigned short* __restrict__ C, const float* __restrict__ bcat) {
  // 768 blocks: XCD owns an 8-row x-band, sweeps 12 W-columns.
  const int flat = (int)blockIdx.x + 64 * (int)blockIdx.y;   // 0..767
  const int xcd = flat & 7, j = flat >> 3;                   // j 0..95
  const int row = xcd * 8 + (j & 7);
  const int col = j >> 3;                                    // 0..11
  gemm_body<EPI_QKV>(A, B, C, bcat, nullptr, DIM, DIM, DIM, DIM, 1.f,
                     row * 256, col * 256, 0, 0, 0, 0);
}

__global__ __launch_bounds__(512, 2) void gemm_exp(
    const unsigned short* __restrict__ A, const unsigned short* __restrict__ B,
    unsigned short* __restrict__ C, float* __restrict__ lsum) {
  // 1024 blocks. XCD x: batch x>>1; PINS a 4-row Q-band (2 MB, L2-resident
  // across 2 rounds) and sweeps 16 K-columns; in-flight set = 2 MB pinned Q
  // + ~4 MB streaming Km with 4x in-round reuse. E-writes are nt (no evict).
  const int flat = (int)blockIdx.x +
                   (int)gridDim.x * ((int)blockIdx.y + (int)gridDim.y * (int)blockIdx.z);
  const int xcd = flat & 7, j = flat >> 3;   // j 0..127
  const int bz   = xcd >> 1;                 // 0..3 (2 XCDs per batch)
  const int rsel = j >> 6;                   // 0..1 (row-band half)
  const int jj   = j & 63;
  const int row  = (xcd & 1) * 8 + rsel * 4 + (jj & 3);   // 0..15
  const int col  = jj >> 2;                               // 0..15
  gemm_body<EPI_EXP>(A, B, C, nullptr, lsum, DIM, DIM, DIM, SEQ, 0.04508422f,
                     row * 256, col * 256, bz,
                     (long)SEQ * DIM, (long)SEQ * DIM, (long)SEQ * SEQ);
}

__global__ __launch_bounds__(512, 2) void gemm_pv(
    const unsigned short* __restrict__ A, const unsigned short* __restrict__ B,
    float* __restrict__ C, float* __restrict__ lsum) {
  const int flat = (int)blockIdx.x +
                   (int)gridDim.x * ((int)blockIdx.y + (int)gridDim.y * (int)blockIdx.z);
  const int nf  = (flat & 7) * 32 + (flat >> 3);   // bijective, 256 = 8 x 32
  const int b   = nf >> 6;
  const int rc  = nf & 63;
  const int row = rc >> 2, col = rc & 3;
  gemm_body<EPI_PV>(A, B, C, nullptr, lsum, SEQ, SEQ, MTOT, DIM, 1.f,
                    row * 256, col * 256, b,
                    (long)SEQ * SEQ, (long)SEQ, (long)SEQ * DIM);
}

extern "C" void kernel_launch(void* const* d_in, const int* in_sizes, int n_in,
                              void* d_out, int out_size, void* d_ws, size_t ws_size,
                              hipStream_t stream) {
  (void)in_sizes; (void)n_in; (void)out_size; (void)ws_size;
  const float* x  = (const float*)d_in[0];
  const float* Wq = (const float*)d_in[1];
  const float* bq = (const float*)d_in[2];
  const float* Wk = (const float*)d_in[3];
  const float* bk = (const float*)d_in[4];
  const float* Wv = (const float*)d_in[5];
  const float* bv = (const float*)d_in[6];
  float* out = (float*)d_out;

  const size_t SALL = (size_t)NB * SEQ * SEQ;
  unsigned short* Q  = (unsigned short*)d_ws;
  unsigned short* Km = Q + EL;
  unsigned short* VT = Km + EL;                  // transposed: VT[e][b*SEQ+s]
  unsigned short* Sb = VT + EL;                  // E = exp(S/32), unnormalized
  unsigned short* WT = Sb + SALL;                // [3072][1024] = WqT|WkT|WvT
  float*          l  = (float*)(WT + (size_t)3 * DIM * DIM);   // [MTOT] row sums
  float*          bc = l + MTOT;                 // bcat[3072]
  unsigned short* xb = Sb;                       // x_bf16 overlaps E (dead after proj)

  prep<<<dim3(EL / 1024), dim3(256), 0, stream>>>(x, xb, bq, bk, bv, bc, l);
  transpose_w3<<<dim3(32, 32, 3), dim3(32, 8), 0, stream>>>(Wq, Wk, Wv, WT);

  // fused QKV projection: [16384,1024] x [3072,1024]^T, epilogue routes Q/K/VT
  gemm_qkv<<<dim3(64, 12), 512, 0, stream>>>(xb, WT, Q, bc);

  // E = exp(QK^T/32) + row sums (register shfl reduce + atomics)
  gemm_exp<<<dim3(SEQ / 256, SEQ / 256, NB), 512, 0, stream>>>(Q, Km, Sb, l);

  // O = (E · V) / l  (fp32 out), XCD-swizzled grid
  gemm_pv<<<dim3(4, 16, 4), 512, 0, stream>>>(Sb, VT, out, l);
}

// Round 14
// 398.199 us; speedup vs baseline: 1.1866x; 1.0615x over previous
//
#include <hip/hip_runtime.h>
#include <hip/hip_bf16.h>
#include <cstdint>

#define SEQ 4096
#define NB 4
#define DIM 1024
#define MTOT (NB * SEQ)   // 16384
constexpr size_t EL = (size_t)MTOT * DIM;

using u16x8  = __attribute__((ext_vector_type(8))) unsigned short;
using bf16x8 = __attribute__((ext_vector_type(8))) __bf16;
using f32x4  = __attribute__((ext_vector_type(4))) float;

__device__ __forceinline__ unsigned short f2bf(float f) {
  return __builtin_bit_cast(unsigned short, __float2bfloat16(f));  // native RNE cvt
}

__device__ __forceinline__ void gload16(const unsigned short* g, unsigned short* l) {
  __builtin_amdgcn_global_load_lds(
      (const __attribute__((address_space(1))) unsigned int*)g,
      (__attribute__((address_space(3))) unsigned int*)l, 16, 0, 0);
}
__device__ __forceinline__ void stage_half(const unsigned short* gsrc, size_t ld,
                                           unsigned short* ldst) {
  gload16(gsrc, ldst);
  gload16(gsrc + 64 * ld, ldst + 64 * 64);
}

#define BAR()   __builtin_amdgcn_s_barrier()
#define FENCE() asm volatile("" ::: "memory")

// ------- prep: x fp32->bf16, bias concat, lsum zero -------
__global__ __launch_bounds__(256) void prep(const float* __restrict__ x,
                                            unsigned short* __restrict__ xb,
                                            const float* __restrict__ bq,
                                            const float* __restrict__ bk,
                                            const float* __restrict__ bv,
                                            float* __restrict__ bc,
                                            float* __restrict__ l) {
  const size_t gid = (size_t)blockIdx.x * 256 + threadIdx.x;
  const size_t i = gid * 4;
  float4 v = *(const float4*)(x + i);
  ushort4 o;
  o.x = f2bf(v.x); o.y = f2bf(v.y); o.z = f2bf(v.z); o.w = f2bf(v.w);
  *(ushort4*)(xb + i) = o;
  if (gid < MTOT) l[gid] = 0.f;
  if (gid < 3 * DIM)
    bc[gid] = gid < DIM ? bq[gid] : gid < 2 * DIM ? bk[gid - DIM] : bv[gid - 2 * DIM];
}

// ------- W fp32 [1024][1024] -> WT bf16, 3 matrices via blockIdx.z -------
__global__ __launch_bounds__(256) void transpose_w3(const float* __restrict__ Wq,
                                                    const float* __restrict__ Wk,
                                                    const float* __restrict__ Wv,
                                                    unsigned short* __restrict__ WT) {
  const float* W = blockIdx.z == 0 ? Wq : blockIdx.z == 1 ? Wk : Wv;
  unsigned short* O = WT + (size_t)blockIdx.z * DIM * DIM;
  __shared__ float tile[32][33];
  const int tx = threadIdx.x, ty = threadIdx.y;
  const int d0 = blockIdx.y * 32, e0 = blockIdx.x * 32;
#pragma unroll
  for (int j = 0; j < 32; j += 8)
    tile[ty + j][tx] = W[(size_t)(d0 + ty + j) * DIM + e0 + tx];
  __syncthreads();
#pragma unroll
  for (int j = 0; j < 32; j += 8)
    O[(size_t)(e0 + ty + j) * DIM + d0 + tx] = f2bf(tile[tx][ty + j]);
}

// ============ 256x256 8-phase BT-GEMM body: C[M,N] = A[M,K] * B^T ============
// 512 thr = 8 waves (2M x 4N); wave tile 128x64; BK=64; LDS 128KiB (2 K-tile bufs).
// Race-free schedule: each phase's ds_reads issued before the phase barrier,
// consumed after it; counted vmcnt(6) keeps prefetch loads in flight.
enum { EPI_QKV = 0, EPI_EXP = 1, EPI_PV = 2 };

template <int EPI>
__device__ __forceinline__ void gemm_body(
    const unsigned short* __restrict__ A, const unsigned short* __restrict__ B,
    void* __restrict__ C, const float* __restrict__ bias, float* __restrict__ lsum,
    int K, int lda, int ldb, int ldc, float scale,
    int row0, int col0, int bz, long sA, long sB, long sC) {
  __shared__ unsigned short sm[2][2][256 * 64];   // 128 KiB
  const int t    = threadIdx.x;
  const int lane = t & 63;
  const int wave = t >> 6;
  const int wm   = wave >> 2;
  const int wn   = wave & 3;
  const int fr   = lane & 15;
  const int g    = lane >> 4;
  const int xr   = (fr & 7) << 4;

  const unsigned short* Ab = A + (size_t)bz * (size_t)sA;
  const unsigned short* Bb = B + (size_t)bz * (size_t)sB;

  const int srow = t >> 3;
  const int scol = ((((t & 7) << 4) ^ ((srow & 7) << 4)) >> 1);
  const unsigned short* gA = Ab + (size_t)(row0 + srow) * (size_t)lda + scol;
  const unsigned short* gB = Bb + (size_t)(col0 + srow) * (size_t)ldb + scol;

  const int arow = wm * 128 + fr;
  const int brow = wn * 64 + fr;
  const int c0 = (((g << 4)) ^ xr) >> 1;
  const int c1 = ((64 | (g << 4)) ^ xr) >> 1;

  f32x4 acc[8][4];
  const f32x4 z4 = {0.f, 0.f, 0.f, 0.f};
#pragma unroll
  for (int i = 0; i < 8; ++i)
#pragma unroll
    for (int j = 0; j < 4; ++j) acc[i][j] = z4;

  const int nt = K >> 6;

  stage_half(gA, lda, &sm[0][0][wave * 512]);
  stage_half(gA + 128 * (size_t)lda, lda, &sm[0][0][8192 + wave * 512]);
  stage_half(gB, ldb, &sm[0][1][wave * 512]);
  stage_half(gB + 128 * (size_t)ldb, ldb, &sm[0][1][8192 + wave * 512]);
  if (nt > 1) {
    stage_half(gB + 64, ldb, &sm[1][1][wave * 512]);
    stage_half(gB + 128 * (size_t)ldb + 64, ldb, &sm[1][1][8192 + wave * 512]);
    stage_half(gA + 64, lda, &sm[1][0][wave * 512]);
    asm volatile("s_waitcnt vmcnt(6)" ::: "memory");
  } else {
    asm volatile("s_waitcnt vmcnt(0)" ::: "memory");
  }
  BAR(); FENCE();

  bf16x8 a0[4][2], a1[4][2], b0[2][2], b1[2][2];

  for (int kt = 0; kt < nt; ++kt) {
    const int p = kt & 1;
    const unsigned short* As  = sm[p][0];
    const unsigned short* Bs2 = sm[p][1];

    // P1: read A0-3 + B0-1 (12), stage T(kt+1).A-hi
#pragma unroll
    for (int mi = 0; mi < 4; ++mi) {
      a0[mi][0] = *(const bf16x8*)(As + (arow + mi * 16) * 64 + c0);
      a0[mi][1] = *(const bf16x8*)(As + (arow + mi * 16) * 64 + c1);
    }
#pragma unroll
    for (int ni = 0; ni < 2; ++ni) {
      b0[ni][0] = *(const bf16x8*)(Bs2 + (brow + ni * 16) * 64 + c0);
      b0[ni][1] = *(const bf16x8*)(Bs2 + (brow + ni * 16) * 64 + c1);
    }
    if (kt + 1 < nt)
      stage_half(gA + 128 * (size_t)lda + (size_t)(kt + 1) * 64, lda,
                 &sm[p ^ 1][0][8192 + wave * 512]);
    FENCE(); BAR(); FENCE();
    __builtin_amdgcn_s_setprio(1);
#pragma unroll
    for (int mi = 0; mi < 4; ++mi)
#pragma unroll
      for (int ni = 0; ni < 2; ++ni) {
        acc[mi][ni] = __builtin_amdgcn_mfma_f32_16x16x32_bf16(a0[mi][0], b0[ni][0], acc[mi][ni], 0, 0, 0);
        acc[mi][ni] = __builtin_amdgcn_mfma_f32_16x16x32_bf16(a0[mi][1], b0[ni][1], acc[mi][ni], 0, 0, 0);
      }
    __builtin_amdgcn_s_setprio(0);
    FENCE(); BAR(); FENCE();

    // P2: read B2-3 (4)
#pragma unroll
    for (int ni = 0; ni < 2; ++ni) {
      b1[ni][0] = *(const bf16x8*)(Bs2 + (brow + (ni + 2) * 16) * 64 + c0);
      b1[ni][1] = *(const bf16x8*)(Bs2 + (brow + (ni + 2) * 16) * 64 + c1);
    }
    FENCE(); BAR(); FENCE();
    __builtin_amdgcn_s_setprio(1);
#pragma unroll
    for (int mi = 0; mi < 4; ++mi)
#pragma unroll
      for (int ni = 0; ni < 2; ++ni) {
        acc[mi][ni + 2] = __builtin_amdgcn_mfma_f32_16x16x32_bf16(a0[mi][0], b1[ni][0], acc[mi][ni + 2], 0, 0, 0);
        acc[mi][ni + 2] = __builtin_amdgcn_mfma_f32_16x16x32_bf16(a0[mi][1], b1[ni][1], acc[mi][ni + 2], 0, 0, 0);
      }
    __builtin_amdgcn_s_setprio(0);
    FENCE(); BAR(); FENCE();

    // P3: read A4-7 (8), stage T(kt+2).B-lo
#pragma unroll
    for (int mi = 0; mi < 4; ++mi) {
      a1[mi][0] = *(const bf16x8*)(As + (arow + (mi + 4) * 16) * 64 + c0);
      a1[mi][1] = *(const bf16x8*)(As + (arow + (mi + 4) * 16) * 64 + c1);
    }
    if (kt + 2 < nt)
      stage_half(gB + (size_t)(kt + 2) * 64, ldb, &sm[p][1][wave * 512]);
    FENCE(); BAR(); FENCE();
    __builtin_amdgcn_s_setprio(1);
#pragma unroll
    for (int mi = 0; mi < 4; ++mi)
#pragma unroll
      for (int ni = 0; ni < 2; ++ni) {
        acc[mi + 4][ni] = __builtin_amdgcn_mfma_f32_16x16x32_bf16(a1[mi][0], b0[ni][0], acc[mi + 4][ni], 0, 0, 0);
        acc[mi + 4][ni] = __builtin_amdgcn_mfma_f32_16x16x32_bf16(a1[mi][1], b0[ni][1], acc[mi + 4][ni], 0, 0, 0);
      }
    __builtin_amdgcn_s_setprio(0);
    FENCE(); BAR(); FENCE();

    // P4: stage T(kt+2).{B-hi,A-lo}; counted vmcnt; MFMA q4
    if (kt + 2 < nt) {
      stage_half(gB + 128 * (size_t)ldb + (size_t)(kt + 2) * 64, ldb,
                 &sm[p][1][8192 + wave * 512]);
      stage_half(gA + (size_t)(kt + 2) * 64, lda, &sm[p][0][wave * 512]);
      asm volatile("s_waitcnt vmcnt(6)" ::: "memory");
    } else {
      asm volatile("s_waitcnt vmcnt(0)" ::: "memory");
    }
    FENCE(); BAR(); FENCE();
    __builtin_amdgcn_s_setprio(1);
#pragma unroll
    for (int mi = 0; mi < 4; ++mi)
#pragma unroll
      for (int ni = 0; ni < 2; ++ni) {
        acc[mi + 4][ni + 2] = __builtin_amdgcn_mfma_f32_16x16x32_bf16(a1[mi][0], b1[ni][0], acc[mi + 4][ni + 2], 0, 0, 0);
        acc[mi + 4][ni + 2] = __builtin_amdgcn_mfma_f32_16x16x32_bf16(a1[mi][1], b1[ni][1], acc[mi + 4][ni + 2], 0, 0, 0);
      }
    __builtin_amdgcn_s_setprio(0);
    FENCE(); BAR(); FENCE();
  }

  // ===================== LDS-staged coalesced epilogues =====================
  char* Lb = (char*)&sm[0][0][0];
  const int rb = (lane >> 4) * 4;

  if constexpr (EPI == EPI_QKV) {
    const int which = col0 >> 10;            // 0=Q 1=K 2=V
    const int lc0   = col0 & 1023;
    unsigned short* Co = (unsigned short*)C + (size_t)which * EL;
    if (which < 2) {
      float bb[4];
#pragma unroll
      for (int ni = 0; ni < 4; ++ni) bb[ni] = bias[col0 + wn * 64 + ni * 16 + fr];
#pragma unroll
      for (int mi = 0; mi < 8; ++mi) {
        const int r0 = wm * 128 + mi * 16 + rb;
#pragma unroll
        for (int ni = 0; ni < 4; ++ni) {
          const int c = wn * 64 + ni * 16 + fr;
#pragma unroll
          for (int j = 0; j < 4; ++j) {
            const int r = r0 + j;
            *(unsigned short*)(Lb + r * 512 + ((c * 2) ^ ((r & 7) << 4))) =
                f2bf(acc[mi][ni][j] + bb[ni]);
          }
        }
      }
      __syncthreads();
#pragma unroll 4
      for (int i = 0; i < 16; ++i) {
        const int G = i * 512 + t;
        const int r = G >> 5, c16 = G & 31;
        u16x8 v = *(const u16x8*)(Lb + r * 512 + ((c16 * 16) ^ ((r & 7) << 4)));
        *(u16x8*)(Co + (size_t)(row0 + r) * DIM + lc0 + c16 * 8) = v;
      }
    } else {
      // V: store transposed through col-major LDS tile
#pragma unroll
      for (int ni = 0; ni < 4; ++ni) {
        const int c = wn * 64 + ni * 16 + fr;
        const float bb = bias[col0 + c];
#pragma unroll
        for (int mi = 0; mi < 8; ++mi) {
          const int r0 = wm * 128 + mi * 16 + rb;
          ushort4 pk;
          pk.x = f2bf(acc[mi][ni][0] + bb);
          pk.y = f2bf(acc[mi][ni][1] + bb);
          pk.z = f2bf(acc[mi][ni][2] + bb);
          pk.w = f2bf(acc[mi][ni][3] + bb);
          *(ushort4*)(Lb + c * 512 + ((r0 * 2) ^ ((c & 7) << 4))) = pk;
        }
      }
      __syncthreads();
#pragma unroll 4
      for (int i = 0; i < 16; ++i) {
        const int G = i * 512 + t;
        const int e = G >> 5, m16 = G & 31;
        u16x8 v = *(const u16x8*)(Lb + e * 512 + ((m16 * 16) ^ ((e & 7) << 4)));
        *(u16x8*)(Co + (size_t)(lc0 + e) * MTOT + row0 + m16 * 8) = v;
      }
    }
  } else if constexpr (EPI == EPI_EXP) {
    // E = exp2(acc*scale); row sums from registers (shfl), coalesced E store.
#pragma unroll
    for (int mi = 0; mi < 8; ++mi)
#pragma unroll
      for (int ni = 0; ni < 4; ++ni)
#pragma unroll
        for (int j = 0; j < 4; ++j)
          acc[mi][ni][j] = exp2f(acc[mi][ni][j] * scale);

#pragma unroll
    for (int mi = 0; mi < 8; ++mi)
#pragma unroll
      for (int j = 0; j < 4; ++j) {
        float s = acc[mi][0][j] + acc[mi][1][j] + acc[mi][2][j] + acc[mi][3][j];
        s += __shfl_xor(s, 1);
        s += __shfl_xor(s, 2);
        s += __shfl_xor(s, 4);
        s += __shfl_xor(s, 8);
        if (fr == 0)
          atomicAdd(&lsum[(size_t)bz * SEQ + row0 + wm * 128 + mi * 16 + rb + j], s);
      }

#pragma unroll
    for (int mi = 0; mi < 8; ++mi) {
      const int r0 = wm * 128 + mi * 16 + rb;
#pragma unroll
      for (int ni = 0; ni < 4; ++ni) {
        const int c = wn * 64 + ni * 16 + fr;
#pragma unroll
        for (int j = 0; j < 4; ++j) {
          const int r = r0 + j;
          *(unsigned short*)(Lb + r * 512 + ((c * 2) ^ ((r & 7) << 4))) =
              f2bf(acc[mi][ni][j]);
        }
      }
    }
    __syncthreads();
    unsigned short* Co = (unsigned short*)C + (size_t)bz * (size_t)sC;
#pragma unroll 4
    for (int i = 0; i < 16; ++i) {
      const int G = i * 512 + t;
      const int r = G >> 5, c16 = G & 31;
      u16x8 v = *(const u16x8*)(Lb + r * 512 + ((c16 * 16) ^ ((r & 7) << 4)));
      *(u16x8*)(Co + (size_t)(row0 + r) * (size_t)ldc + col0 + c16 * 8) = v;
    }
  } else {  // EPI_PV: fp32 out / lsum[row], two 128-row halves through LDS
    float* Co = (float*)C + (size_t)bz * (size_t)sC;
#pragma unroll
    for (int h = 0; h < 2; ++h) {
      if (h) __syncthreads();
      if (wm == h) {
#pragma unroll
        for (int mi = 0; mi < 8; ++mi) {
          const int r0 = mi * 16 + rb;
#pragma unroll
          for (int ni = 0; ni < 4; ++ni) {
            const int c = wn * 64 + ni * 16 + fr;
#pragma unroll
            for (int j = 0; j < 4; ++j) {
              const int r = r0 + j;
              *(float*)(Lb + r * 1024 + ((c * 4) ^ ((r & 7) << 4))) = acc[mi][ni][j];
            }
          }
        }
      }
      __syncthreads();
#pragma unroll 4
      for (int i = 0; i < 16; ++i) {
        const int G = i * 512 + t;
        const int r = G >> 6, c4 = G & 63;
        f32x4 v = *(const f32x4*)(Lb + r * 1024 + ((c4 * 16) ^ ((r & 7) << 4)));
        const size_t grow = (size_t)row0 + h * 128 + r;
        const float inv = 1.0f / lsum[(size_t)bz * SEQ + grow];
        v *= inv;
        *(f32x4*)(Co + grow * (size_t)ldc + col0 + c4 * 4) = v;
      }
    }
  }
}

// ---------------- wrappers with XCD-locality block remaps (R8-verified) ----------------
__global__ __launch_bounds__(512, 2) void gemm_qkv(
    const unsigned short* __restrict__ A, const unsigned short* __restrict__ B,
    unsigned short* __restrict__ C, const float* __restrict__ bcat) {
  // 768 blocks: XCD owns an 8-row x-band (4 MB), sweeps 12 W-columns.
  const int flat = (int)blockIdx.x + 64 * (int)blockIdx.y;   // 0..767
  const int xcd = flat & 7, j = flat >> 3;                   // j 0..95
  const int row = xcd * 8 + (j & 7);
  const int col = j >> 3;                                    // 0..11
  gemm_body<EPI_QKV>(A, B, C, bcat, nullptr, DIM, DIM, DIM, DIM, 1.f,
                     row * 256, col * 256, 0, 0, 0, 0);
}

__global__ __launch_bounds__(512, 2) void gemm_exp(
    const unsigned short* __restrict__ A, const unsigned short* __restrict__ B,
    unsigned short* __restrict__ C, float* __restrict__ lsum) {
  // 1024 blocks. XCD x owns Q-row band (x&3)*4..+3 for batches {0,1}/{2,3};
  // sweeps 16 K-columns per batch. (R8: halves HBM FETCH at equal dur.)
  const int flat = (int)blockIdx.x +
                   (int)gridDim.x * ((int)blockIdx.y + (int)gridDim.y * (int)blockIdx.z);
  const int xcd = flat & 7, j = flat >> 3;   // j 0..127
  const int bz  = (xcd >> 2) * 2 + (j >> 6); // 0..3
  const int jj  = j & 63;
  const int row = (xcd & 3) * 4 + (jj & 3);  // 0..15
  const int col = jj >> 2;                   // 0..15
  gemm_body<EPI_EXP>(A, B, C, nullptr, lsum, DIM, DIM, DIM, SEQ, 0.04508422f,
                     row * 256, col * 256, bz,
                     (long)SEQ * DIM, (long)SEQ * DIM, (long)SEQ * SEQ);
}

__global__ __launch_bounds__(512, 2) void gemm_pv(
    const unsigned short* __restrict__ A, const unsigned short* __restrict__ B,
    float* __restrict__ C, float* __restrict__ lsum) {
  // 256 blocks, XCD-swizzled: each XCD gets 8 row-tiles x 4 col-tiles
  const int flat = (int)blockIdx.x +
                   (int)gridDim.x * ((int)blockIdx.y + (int)gridDim.y * (int)blockIdx.z);
  const int nf  = (flat & 7) * 32 + (flat >> 3);   // bijective, 256 = 8 x 32
  const int b   = nf >> 6;
  const int rc  = nf & 63;
  const int row = rc >> 2, col = rc & 3;
  gemm_body<EPI_PV>(A, B, C, nullptr, lsum, SEQ, SEQ, MTOT, DIM, 1.f,
                    row * 256, col * 256, b,
                    (long)SEQ * SEQ, (long)SEQ, (long)SEQ * DIM);
}

extern "C" void kernel_launch(void* const* d_in, const int* in_sizes, int n_in,
                              void* d_out, int out_size, void* d_ws, size_t ws_size,
                              hipStream_t stream) {
  (void)in_sizes; (void)n_in; (void)out_size; (void)ws_size;
  const float* x  = (const float*)d_in[0];
  const float* Wq = (const float*)d_in[1];
  const float* bq = (const float*)d_in[2];
  const float* Wk = (const float*)d_in[3];
  const float* bk = (const float*)d_in[4];
  const float* Wv = (const float*)d_in[5];
  const float* bv = (const float*)d_in[6];
  float* out = (float*)d_out;

  const size_t SALL = (size_t)NB * SEQ * SEQ;
  unsigned short* Q  = (unsigned short*)d_ws;
  unsigned short* Km = Q + EL;
  unsigned short* VT = Km + EL;                  // transposed: VT[e][b*SEQ+s]
  unsigned short* Sb = VT + EL;                  // E = exp(S/32), unnormalized
  unsigned short* WT = Sb + SALL;                // [3072][1024] = WqT|WkT|WvT
  float*          l  = (float*)(WT + (size_t)3 * DIM * DIM);   // [MTOT] row sums
  float*          bc = l + MTOT;                 // bcat[3072]
  unsigned short* xb = Sb;                       // x_bf16 overlaps E (dead after proj)

  prep<<<dim3(EL / 1024), dim3(256), 0, stream>>>(x, xb, bq, bk, bv, bc, l);
  transpose_w3<<<dim3(32, 32, 3), dim3(32, 8), 0, stream>>>(Wq, Wk, Wv, WT);

  // fused QKV projection: [16384,1024] x [3072,1024]^T, epilogue routes Q/K/VT
  gemm_qkv<<<dim3(64, 12), 512, 0, stream>>>(xb, WT, Q, bc);

  // E = exp(QK^T/32) + row sums (register shfl reduce + atomics)
  gemm_exp<<<dim3(SEQ / 256, SEQ / 256, NB), 512, 0, stream>>>(Q, Km, Sb, l);

  // O = (E · V) / l  (fp32 out), XCD-swizzled grid
  gemm_pv<<<dim3(4, 16, 4), 512, 0, stream>>>(Sb, VT, out, l);
}